// Round 1
// 1361.950 us; speedup vs baseline: 1.0211x; 1.0211x over previous
//
#include <hip/hip_runtime.h>

// DependencyGNN: 2-layer GCN + global mean pool.
// R3: GEMM tile widened to BN=256 (= full output width) so the fp32 A-panel
// is fetched from HBM exactly once (was twice with BN=128: ~820 MB saved
// across the two GEMMs). 512 threads / 8 waves (2x4), each wave 64x64 via
// 4x4 MFMA 16x16x32. Register prefetch of next K-tile issued right after
// the barrier (T14-style) hides HBM latency under MFMA.
// Aggregation / pool / preprocessing unchanged from R2.

#define N_NODES_C 200000
#define N_EDGES_C 400000
#define IN_CH_C 768
#define HID_C 256
#define NUM_GRAPHS_C 8000

typedef __attribute__((ext_vector_type(8))) short short8;   // 8 bf16 = 4 VGPRs
typedef __attribute__((ext_vector_type(4))) float f32x4;    // MFMA accum

__device__ __forceinline__ unsigned short f2bf(float f) {
  union { float f; unsigned u; } v; v.f = f;
  unsigned r = v.u + 0x7FFFu + ((v.u >> 16) & 1u);  // RNE
  return (unsigned short)(r >> 16);
}

// ---------------- preprocessing ----------------

__global__ void zero2_kernel(int* __restrict__ a, int* __restrict__ b, int n) {
  int i = blockIdx.x * blockDim.x + threadIdx.x;
  if (i < n) { a[i] = 0; b[i] = 0; }
}

__global__ void hist_kernel(const int* __restrict__ dst, int* __restrict__ deg, int E) {
  int e = blockIdx.x * blockDim.x + threadIdx.x;
  if (e < E) atomicAdd(&deg[dst[e]], 1);
}

__global__ void dinv_kernel(const int* __restrict__ deg, float* __restrict__ dinv, int n) {
  int i = blockIdx.x * blockDim.x + threadIdx.x;
  if (i < n) dinv[i] = rsqrtf((float)(deg[i] + 1));  // +1 self-loop
}

__global__ __launch_bounds__(256) void scan1_kernel(const int* __restrict__ deg,
                                                    int* __restrict__ offs,
                                                    int* __restrict__ bsums, int n) {
  __shared__ int s[256];
  int tid = threadIdx.x;
  int i = blockIdx.x * 256 + tid;
  int v = (i < n) ? deg[i] : 0;
  s[tid] = v;
  __syncthreads();
  for (int d = 1; d < 256; d <<= 1) {
    int t = (tid >= d) ? s[tid - d] : 0;
    __syncthreads();
    s[tid] += t;
    __syncthreads();
  }
  if (i < n) offs[i] = s[tid] - v;
  if (tid == 255) bsums[blockIdx.x] = s[255];
}

__global__ __launch_bounds__(1024) void scan2_kernel(int* __restrict__ bsums, int nb) {
  __shared__ int s[1024];
  int tid = threadIdx.x;
  int v = (tid < nb) ? bsums[tid] : 0;
  s[tid] = v;
  __syncthreads();
  for (int d = 1; d < 1024; d <<= 1) {
    int t = (tid >= d) ? s[tid - d] : 0;
    __syncthreads();
    s[tid] += t;
    __syncthreads();
  }
  if (tid < nb) bsums[tid] = s[tid] - v;
}

__global__ void scan3_kernel(int* __restrict__ offs, const int* __restrict__ bsums, int n) {
  int i = blockIdx.x * 256 + threadIdx.x;
  if (i < n) offs[i] += bsums[blockIdx.x];
  if (i == 0) offs[n] = N_EDGES_C;
}

__global__ void scatter_kernel(const int* __restrict__ esrc_in, const int* __restrict__ edst_in,
                               const int* __restrict__ offs, int* __restrict__ cursor,
                               const float* __restrict__ dinv,
                               int* __restrict__ esrc, float* __restrict__ enorm, int E) {
  int e = blockIdx.x * blockDim.x + threadIdx.x;
  if (e >= E) return;
  int s = esrc_in[e], d = edst_in[e];
  int pos = offs[d] + atomicAdd(&cursor[d], 1);
  esrc[pos] = s;
  enorm[pos] = dinv[s] * dinv[d];
}

// ---------------- weight prep: WT[n*K+k] = bf16(W[k*N+n]) ----------------

__global__ void wprep_kernel(const float* __restrict__ W, unsigned short* __restrict__ WT,
                             int K, int N, int total) {
  int idx = blockIdx.x * blockDim.x + threadIdx.x;
  if (idx >= total) return;
  int n = idx / K, k = idx - n * K;
  WT[idx] = f2bf(W[(size_t)k * N + n]);
}

// ---------------- bf16 MFMA GEMM: C[M,256] = A[M,K] x BT[256,K]^T ----------------
// 128x256 tile (full N), 512 threads = 8 waves (2x4), each wave 64x64 via
// 4x4 MFMA 16x16x32. A fp32 converted to bf16 during staging; BT already
// bf16 (pre-transposed weights). Next K-tile global loads issued right
// after the first barrier so HBM latency hides under the MFMA cluster.

#define BM 128
#define BN 256
#define BK 32
#define LDT 40  // BK + 8 pad (ushort units; 80 B row stride -> 2-way-max frag reads)

__global__ __launch_bounds__(512) void gemm_bf16_kernel(
    const float* __restrict__ A, const unsigned short* __restrict__ BT,
    float* __restrict__ C, int M, int K) {
  __shared__ unsigned short As[BM * LDT];   // 10240 * 2B = 20 KiB
  __shared__ unsigned short Bs[BN * LDT];   // 20480 * 2B = 40 KiB
  const int tid = threadIdx.x;
  const int row0 = blockIdx.x * BM;
  const int lane = tid & 63;
  const int w = tid >> 6;            // 0..7
  const int wm = (w >> 2) * 64;      // 0 / 64
  const int wn = (w & 3) * 64;       // 0 / 64 / 128 / 192
  const int r16 = lane & 15, quad = lane >> 4;

  f32x4 acc[4][4] = {};

  // staging assignments
  const int arow = tid >> 2;          // 0..127
  const int ak = (tid & 3) * 8;       // 0,8,16,24  (8 fp32 -> 8 bf16 per thread)
  const int brow = tid >> 1;          // 0..255
  const int bk = (tid & 1) * 16;      // 0,16       (16 bf16 per thread)

  const bool avalid = (row0 + arow) < M;
  const float* aptr = &A[(size_t)(row0 + arow) * K + ak];
  const unsigned short* bptr = &BT[(size_t)brow * K + bk];

  // prefetch k0 = 0
  float av[8];
  uint4 bv0, bv1;
  if (avalid) {
    *(float4*)&av[0] = *(const float4*)&aptr[0];
    *(float4*)&av[4] = *(const float4*)&aptr[4];
  } else {
#pragma unroll
    for (int i = 0; i < 8; ++i) av[i] = 0.f;
  }
  bv0 = *(const uint4*)&bptr[0];
  bv1 = *(const uint4*)&bptr[8];

  for (int k0 = 0; k0 < K; k0 += BK) {
    // write staged regs (tile k0) to LDS
    {
      unsigned short hb[8];
#pragma unroll
      for (int i = 0; i < 8; ++i) hb[i] = f2bf(av[i]);
      *(uint4*)&As[arow * LDT + ak] = *(uint4*)&hb[0];
      *(uint4*)&Bs[brow * LDT + bk] = bv0;
      *(uint4*)&Bs[brow * LDT + bk + 8] = bv1;
    }
    __syncthreads();
    // issue next-tile global loads; they complete under the MFMA cluster
    if (k0 + BK < K) {
      if (avalid) {
        *(float4*)&av[0] = *(const float4*)&aptr[k0 + BK + 0];
        *(float4*)&av[4] = *(const float4*)&aptr[k0 + BK + 4];
      }
      bv0 = *(const uint4*)&bptr[k0 + BK + 0];
      bv1 = *(const uint4*)&bptr[k0 + BK + 8];
    }

    short8 af[4], bfr[4];
#pragma unroll
    for (int i = 0; i < 4; ++i)
      af[i] = *(const short8*)&As[(wm + i * 16 + r16) * LDT + quad * 8];
#pragma unroll
    for (int j = 0; j < 4; ++j)
      bfr[j] = *(const short8*)&Bs[(wn + j * 16 + r16) * LDT + quad * 8];
#pragma unroll
    for (int i = 0; i < 4; ++i)
#pragma unroll
      for (int j = 0; j < 4; ++j)
        acc[i][j] = __builtin_amdgcn_mfma_f32_16x16x32_bf16(af[i], bfr[j], acc[i][j], 0, 0, 0);
    __syncthreads();
  }

  // epilogue: C/D layout col=lane&15, row=quad*4+reg (m89-verified)
#pragma unroll
  for (int i = 0; i < 4; ++i) {
#pragma unroll
    for (int r = 0; r < 4; ++r) {
      int gr = row0 + wm + i * 16 + quad * 4 + r;
      if (gr < M) {
#pragma unroll
        for (int j = 0; j < 4; ++j)
          C[(size_t)gr * HID_C + wn + j * 16 + r16] = acc[i][j][r];
      }
    }
  }
}

// ---------------- normalized aggregation: one wave per node ----------------

__global__ __launch_bounds__(256) void aggregate_kernel(
    const float* __restrict__ t, float* __restrict__ out,
    const int* __restrict__ offs, const int* __restrict__ esrc,
    const float* __restrict__ enorm, const float* __restrict__ dinv,
    const float* __restrict__ bias, int do_relu) {
  int wid = (int)(((unsigned)blockIdx.x * blockDim.x + threadIdx.x) >> 6);
  int lane = threadIdx.x & 63;
  if (wid >= N_NODES_C) return;
  int node = wid;
  float di = dinv[node];
  float sn = di * di;
  const float4 tv = *(const float4*)&t[(size_t)node * HID_C + lane * 4];
  float4 acc = make_float4(tv.x * sn, tv.y * sn, tv.z * sn, tv.w * sn);
  int beg = offs[node], end = offs[node + 1];
  for (int p = beg; p < end; ++p) {
    int s = esrc[p];
    float w = enorm[p];
    const float4 v = *(const float4*)&t[(size_t)s * HID_C + lane * 4];
    acc.x += v.x * w; acc.y += v.y * w; acc.z += v.z * w; acc.w += v.w * w;
  }
  const float4 bv = *(const float4*)&bias[lane * 4];
  acc.x += bv.x; acc.y += bv.y; acc.z += bv.z; acc.w += bv.w;
  if (do_relu) {
    acc.x = fmaxf(acc.x, 0.f); acc.y = fmaxf(acc.y, 0.f);
    acc.z = fmaxf(acc.z, 0.f); acc.w = fmaxf(acc.w, 0.f);
  }
  *(float4*)&out[(size_t)node * HID_C + lane * 4] = acc;
}

// ---------------- mean pool ----------------

__device__ __forceinline__ int lower_bound_dev(const int* __restrict__ a, int n, int key) {
  int lo = 0, hi = n;
  while (lo < hi) {
    int mid = (lo + hi) >> 1;
    if (a[mid] < key) lo = mid + 1; else hi = mid;
  }
  return lo;
}

__global__ __launch_bounds__(256) void pool_kernel(const float* __restrict__ h,
                                                   const int* __restrict__ batch,
                                                   float* __restrict__ out) {
  int wid = (int)(((unsigned)blockIdx.x * blockDim.x + threadIdx.x) >> 6);
  int lane = threadIdx.x & 63;
  if (wid >= NUM_GRAPHS_C) return;
  int g = wid;
  int lo = lower_bound_dev(batch, N_NODES_C, g);
  int hi = lower_bound_dev(batch, N_NODES_C, g + 1);
  float4 acc = make_float4(0.f, 0.f, 0.f, 0.f);
  for (int i = lo; i < hi; ++i) {
    const float4 v = *(const float4*)&h[(size_t)i * HID_C + lane * 4];
    acc.x += v.x; acc.y += v.y; acc.z += v.z; acc.w += v.w;
  }
  float inv = 1.0f / fmaxf((float)(hi - lo), 1.0f);
  acc.x *= inv; acc.y *= inv; acc.z *= inv; acc.w *= inv;
  *(float4*)&out[(size_t)g * HID_C + lane * 4] = acc;
}

// ---------------- launch ----------------

extern "C" void kernel_launch(void* const* d_in, const int* in_sizes, int n_in,
                              void* d_out, int out_size, void* d_ws, size_t ws_size,
                              hipStream_t stream) {
  (void)in_sizes; (void)n_in; (void)out_size; (void)ws_size;
  const float* x  = (const float*)d_in[0];
  const float* W1 = (const float*)d_in[1];
  const float* b1 = (const float*)d_in[2];
  const float* W2 = (const float*)d_in[3];
  const float* b2 = (const float*)d_in[4];
  const int* edge_index = (const int*)d_in[5];
  const int* batch = (const int*)d_in[6];
  const int* e_src = edge_index;
  const int* e_dst = edge_index + N_EDGES_C;
  float* out = (float*)d_out;

  // workspace layout
  float* t      = (float*)d_ws;
  float* h      = t + (size_t)N_NODES_C * HID_C;
  float* dinv   = h + (size_t)N_NODES_C * HID_C;
  int*   deg    = (int*)(dinv + N_NODES_C);
  int*   offs   = deg + N_NODES_C;
  int*   cursor = offs + (N_NODES_C + 64);
  int*   esrc   = cursor + N_NODES_C;
  float* enorm  = (float*)(esrc + N_EDGES_C);
  int*   bsums  = (int*)(enorm + N_EDGES_C);
  // W1T/W2T alias the cursor region (524 KB < 800 KB): cursor is dead after
  // scatter_kernel, and wprep_* launch AFTER scatter. 16B-aligned.
  unsigned short* W1T = (unsigned short*)cursor;
  unsigned short* W2T = W1T + (size_t)IN_CH_C * HID_C;

  const int NB = (N_NODES_C + 255) / 256;
  const int EB = (N_EDGES_C + 255) / 256;

  zero2_kernel<<<NB, 256, 0, stream>>>(deg, cursor, N_NODES_C);
  hist_kernel<<<EB, 256, 0, stream>>>(e_dst, deg, N_EDGES_C);
  scan1_kernel<<<NB, 256, 0, stream>>>(deg, offs, bsums, N_NODES_C);
  scan2_kernel<<<1, 1024, 0, stream>>>(bsums, NB);
  scan3_kernel<<<NB, 256, 0, stream>>>(offs, bsums, N_NODES_C);
  dinv_kernel<<<NB, 256, 0, stream>>>(deg, dinv, N_NODES_C);
  scatter_kernel<<<EB, 256, 0, stream>>>(e_src, e_dst, offs, cursor, dinv, esrc, enorm, N_EDGES_C);

  // weight prep (after scatter: W1T/W2T alias cursor)
  wprep_kernel<<<(IN_CH_C * HID_C + 255) / 256, 256, 0, stream>>>(W1, W1T, IN_CH_C, HID_C, IN_CH_C * HID_C);
  wprep_kernel<<<(HID_C * HID_C + 255) / 256, 256, 0, stream>>>(W2, W2T, HID_C, HID_C, HID_C * HID_C);

  dim3 g1((N_NODES_C + BM - 1) / BM);  // 1563 blocks, full-width N tiles
  gemm_bf16_kernel<<<g1, 512, 0, stream>>>(x, W1T, t, N_NODES_C, IN_CH_C);
  aggregate_kernel<<<(N_NODES_C * 64 + 255) / 256, 256, 0, stream>>>(
      t, h, offs, esrc, enorm, dinv, b1, 1);
  gemm_bf16_kernel<<<g1, 512, 0, stream>>>(h, W2T, t, N_NODES_C, HID_C);
  aggregate_kernel<<<(N_NODES_C * 64 + 255) / 256, 256, 0, stream>>>(
      t, h, offs, esrc, enorm, dinv, b2, 0);
  pool_kernel<<<(NUM_GRAPHS_C * 64 + 255) / 256, 256, 0, stream>>>(h, batch, out);
}

// Round 2
// 1198.433 us; speedup vs baseline: 1.1604x; 1.1364x over previous
//
#include <hip/hip_runtime.h>

// DependencyGNN: 2-layer GCN + global mean pool.
// R4: intermediate-traffic cut.
//  - t1 (GEMM1 out) and h1 (layer-1 out) stored as bf16. h1-bf16 is
//    numerically free (GEMM2 rounded its input to bf16 anyway); t1-bf16 adds
//    one rounding to the agg1 inputs (~1 ULP in h1).
//  - agg2 + global mean pool fused: h2 never materialized (saves 410 MB).
//    Layer-2 arithmetic stays fp32 with identical summation order.
//  - GEMM templated on A dtype (fp32-convert vs bf16-direct) and C dtype.
// GEMM tile/schedule and preprocessing unchanged from R3.

#define N_NODES_C 200000
#define N_EDGES_C 400000
#define IN_CH_C 768
#define HID_C 256
#define NUM_GRAPHS_C 8000

typedef __attribute__((ext_vector_type(8))) short short8;   // 8 bf16 = 4 VGPRs
typedef __attribute__((ext_vector_type(4))) float f32x4;    // MFMA accum

__device__ __forceinline__ unsigned short f2bf(float f) {
  union { float f; unsigned u; } v; v.f = f;
  unsigned r = v.u + 0x7FFFu + ((v.u >> 16) & 1u);  // RNE
  return (unsigned short)(r >> 16);
}
__device__ __forceinline__ float bf2f(unsigned short h) {
  union { unsigned u; float f; } v; v.u = ((unsigned)h) << 16;
  return v.f;
}

// ---------------- preprocessing ----------------

__global__ void zero2_kernel(int* __restrict__ a, int* __restrict__ b, int n) {
  int i = blockIdx.x * blockDim.x + threadIdx.x;
  if (i < n) { a[i] = 0; b[i] = 0; }
}

__global__ void hist_kernel(const int* __restrict__ dst, int* __restrict__ deg, int E) {
  int e = blockIdx.x * blockDim.x + threadIdx.x;
  if (e < E) atomicAdd(&deg[dst[e]], 1);
}

__global__ void dinv_kernel(const int* __restrict__ deg, float* __restrict__ dinv, int n) {
  int i = blockIdx.x * blockDim.x + threadIdx.x;
  if (i < n) dinv[i] = rsqrtf((float)(deg[i] + 1));  // +1 self-loop
}

__global__ __launch_bounds__(256) void scan1_kernel(const int* __restrict__ deg,
                                                    int* __restrict__ offs,
                                                    int* __restrict__ bsums, int n) {
  __shared__ int s[256];
  int tid = threadIdx.x;
  int i = blockIdx.x * 256 + tid;
  int v = (i < n) ? deg[i] : 0;
  s[tid] = v;
  __syncthreads();
  for (int d = 1; d < 256; d <<= 1) {
    int t = (tid >= d) ? s[tid - d] : 0;
    __syncthreads();
    s[tid] += t;
    __syncthreads();
  }
  if (i < n) offs[i] = s[tid] - v;
  if (tid == 255) bsums[blockIdx.x] = s[255];
}

__global__ __launch_bounds__(1024) void scan2_kernel(int* __restrict__ bsums, int nb) {
  __shared__ int s[1024];
  int tid = threadIdx.x;
  int v = (tid < nb) ? bsums[tid] : 0;
  s[tid] = v;
  __syncthreads();
  for (int d = 1; d < 1024; d <<= 1) {
    int t = (tid >= d) ? s[tid - d] : 0;
    __syncthreads();
    s[tid] += t;
    __syncthreads();
  }
  if (tid < nb) bsums[tid] = s[tid] - v;
}

__global__ void scan3_kernel(int* __restrict__ offs, const int* __restrict__ bsums, int n) {
  int i = blockIdx.x * 256 + threadIdx.x;
  if (i < n) offs[i] += bsums[blockIdx.x];
  if (i == 0) offs[n] = N_EDGES_C;
}

__global__ void scatter_kernel(const int* __restrict__ esrc_in, const int* __restrict__ edst_in,
                               const int* __restrict__ offs, int* __restrict__ cursor,
                               const float* __restrict__ dinv,
                               int* __restrict__ esrc, float* __restrict__ enorm, int E) {
  int e = blockIdx.x * blockDim.x + threadIdx.x;
  if (e >= E) return;
  int s = esrc_in[e], d = edst_in[e];
  int pos = offs[d] + atomicAdd(&cursor[d], 1);
  esrc[pos] = s;
  enorm[pos] = dinv[s] * dinv[d];
}

// ---------------- weight prep: WT[n*K+k] = bf16(W[k*N+n]) ----------------

__global__ void wprep_kernel(const float* __restrict__ W, unsigned short* __restrict__ WT,
                             int K, int N, int total) {
  int idx = blockIdx.x * blockDim.x + threadIdx.x;
  if (idx >= total) return;
  int n = idx / K, k = idx - n * K;
  WT[idx] = f2bf(W[(size_t)k * N + n]);
}

// ---------------- bf16 MFMA GEMM: C[M,256] = A[M,K] x BT[256,K]^T ----------------
// 128x256 tile (full N), 512 threads = 8 waves (2x4), each wave 64x64 via
// 4x4 MFMA 16x16x32. Register prefetch of next K-tile right after the
// barrier hides HBM latency under the MFMA cluster.
// ABF16: A is bf16 (direct copy) vs fp32 (convert during staging).
// CBF16: C stored as bf16 vs fp32.

#define BM 128
#define BN 256
#define BK 32
#define LDT 40  // BK + 8 pad (ushort units; 80 B row stride -> 2-way-max frag reads)

template <int ABF16, int CBF16>
__global__ __launch_bounds__(512) void gemm_kernel(
    const void* __restrict__ Av, const unsigned short* __restrict__ BT,
    void* __restrict__ Cv, int M, int K) {
  __shared__ unsigned short As[BM * LDT];   // 20 KiB
  __shared__ unsigned short Bs[BN * LDT];   // 40 KiB
  const int tid = threadIdx.x;
  const int row0 = blockIdx.x * BM;
  const int lane = tid & 63;
  const int w = tid >> 6;            // 0..7
  const int wm = (w >> 2) * 64;      // 0 / 64
  const int wn = (w & 3) * 64;       // 0 / 64 / 128 / 192
  const int r16 = lane & 15, quad = lane >> 4;

  f32x4 acc[4][4] = {};

  const int arow = tid >> 2;          // 0..127
  const int ak = (tid & 3) * 8;       // 0,8,16,24  (8 elems per thread)
  const int brow = tid >> 1;          // 0..255
  const int bk = (tid & 1) * 16;      // 0,16       (16 bf16 per thread)

  const bool avalid = (row0 + arow) < M;
  const float* aptr32 = &((const float*)Av)[(size_t)(row0 + arow) * K + ak];
  const unsigned short* aptr16 = &((const unsigned short*)Av)[(size_t)(row0 + arow) * K + ak];
  const unsigned short* bptr = &BT[(size_t)brow * K + bk];

  // prefetch k0 = 0
  float av[8];
  uint4 avb = make_uint4(0, 0, 0, 0);
  uint4 bv0, bv1;
  if constexpr (ABF16) {
    if (avalid) avb = *(const uint4*)&aptr16[0];
  } else {
    if (avalid) {
      *(float4*)&av[0] = *(const float4*)&aptr32[0];
      *(float4*)&av[4] = *(const float4*)&aptr32[4];
    } else {
#pragma unroll
      for (int i = 0; i < 8; ++i) av[i] = 0.f;
    }
  }
  bv0 = *(const uint4*)&bptr[0];
  bv1 = *(const uint4*)&bptr[8];

  for (int k0 = 0; k0 < K; k0 += BK) {
    // write staged regs (tile k0) to LDS
    if constexpr (ABF16) {
      *(uint4*)&As[arow * LDT + ak] = avb;
    } else {
      unsigned short hb[8];
#pragma unroll
      for (int i = 0; i < 8; ++i) hb[i] = f2bf(av[i]);
      *(uint4*)&As[arow * LDT + ak] = *(uint4*)&hb[0];
    }
    *(uint4*)&Bs[brow * LDT + bk] = bv0;
    *(uint4*)&Bs[brow * LDT + bk + 8] = bv1;
    __syncthreads();
    // issue next-tile global loads; they complete under the MFMA cluster
    if (k0 + BK < K) {
      if constexpr (ABF16) {
        if (avalid) avb = *(const uint4*)&aptr16[k0 + BK];
      } else {
        if (avalid) {
          *(float4*)&av[0] = *(const float4*)&aptr32[k0 + BK + 0];
          *(float4*)&av[4] = *(const float4*)&aptr32[k0 + BK + 4];
        }
      }
      bv0 = *(const uint4*)&bptr[k0 + BK + 0];
      bv1 = *(const uint4*)&bptr[k0 + BK + 8];
    }

    short8 af[4], bfr[4];
#pragma unroll
    for (int i = 0; i < 4; ++i)
      af[i] = *(const short8*)&As[(wm + i * 16 + r16) * LDT + quad * 8];
#pragma unroll
    for (int j = 0; j < 4; ++j)
      bfr[j] = *(const short8*)&Bs[(wn + j * 16 + r16) * LDT + quad * 8];
#pragma unroll
    for (int i = 0; i < 4; ++i)
#pragma unroll
      for (int j = 0; j < 4; ++j)
        acc[i][j] = __builtin_amdgcn_mfma_f32_16x16x32_bf16(af[i], bfr[j], acc[i][j], 0, 0, 0);
    __syncthreads();
  }

  // epilogue: C/D layout col=lane&15, row=quad*4+reg (m89-verified)
#pragma unroll
  for (int i = 0; i < 4; ++i) {
#pragma unroll
    for (int r = 0; r < 4; ++r) {
      int gr = row0 + wm + i * 16 + quad * 4 + r;
      if (gr < M) {
        if constexpr (CBF16) {
          unsigned short* C = (unsigned short*)Cv;
#pragma unroll
          for (int j = 0; j < 4; ++j)
            C[(size_t)gr * HID_C + wn + j * 16 + r16] = f2bf(acc[i][j][r]);
        } else {
          float* C = (float*)Cv;
#pragma unroll
          for (int j = 0; j < 4; ++j)
            C[(size_t)gr * HID_C + wn + j * 16 + r16] = acc[i][j][r];
        }
      }
    }
  }
}

// ---------------- layer-1 aggregation (bf16 in/out): one wave per node ----------------

__global__ __launch_bounds__(256) void aggregate_bf_kernel(
    const unsigned short* __restrict__ t, unsigned short* __restrict__ out,
    const int* __restrict__ offs, const int* __restrict__ esrc,
    const float* __restrict__ enorm, const float* __restrict__ dinv,
    const float* __restrict__ bias) {
  int wid = (int)(((unsigned)blockIdx.x * blockDim.x + threadIdx.x) >> 6);
  int lane = threadIdx.x & 63;
  if (wid >= N_NODES_C) return;
  int node = wid;
  float di = dinv[node];
  float sn = di * di;
  ushort4 tv = *(const ushort4*)&t[(size_t)node * HID_C + lane * 4];
  float4 acc = make_float4(bf2f(tv.x) * sn, bf2f(tv.y) * sn,
                           bf2f(tv.z) * sn, bf2f(tv.w) * sn);
  int beg = offs[node], end = offs[node + 1];
  for (int p = beg; p < end; ++p) {
    int s = esrc[p];
    float wgt = enorm[p];
    ushort4 v = *(const ushort4*)&t[(size_t)s * HID_C + lane * 4];
    acc.x += bf2f(v.x) * wgt; acc.y += bf2f(v.y) * wgt;
    acc.z += bf2f(v.z) * wgt; acc.w += bf2f(v.w) * wgt;
  }
  const float4 bv = *(const float4*)&bias[lane * 4];
  acc.x += bv.x; acc.y += bv.y; acc.z += bv.z; acc.w += bv.w;
  acc.x = fmaxf(acc.x, 0.f); acc.y = fmaxf(acc.y, 0.f);
  acc.z = fmaxf(acc.z, 0.f); acc.w = fmaxf(acc.w, 0.f);
  ushort4 o;
  o.x = f2bf(acc.x); o.y = f2bf(acc.y); o.z = f2bf(acc.z); o.w = f2bf(acc.w);
  *(ushort4*)&out[(size_t)node * HID_C + lane * 4] = o;
}

// ---------------- fused layer-2 aggregation + mean pool: one wave per graph ----------------

__device__ __forceinline__ int lower_bound_dev(const int* __restrict__ a, int n, int key) {
  int lo = 0, hi = n;
  while (lo < hi) {
    int mid = (lo + hi) >> 1;
    if (a[mid] < key) lo = mid + 1; else hi = mid;
  }
  return lo;
}

__global__ __launch_bounds__(256) void agg_pool_kernel(
    const float* __restrict__ t, const int* __restrict__ offs,
    const int* __restrict__ esrc, const float* __restrict__ enorm,
    const float* __restrict__ dinv, const float* __restrict__ bias,
    const int* __restrict__ batch, float* __restrict__ out) {
  int wid = (int)(((unsigned)blockIdx.x * blockDim.x + threadIdx.x) >> 6);
  int lane = threadIdx.x & 63;
  if (wid >= NUM_GRAPHS_C) return;
  int g = wid;
  int lo = lower_bound_dev(batch, N_NODES_C, g);
  int hi = lower_bound_dev(batch, N_NODES_C, g + 1);
  const float4 bv = *(const float4*)&bias[lane * 4];
  float4 gacc = make_float4(0.f, 0.f, 0.f, 0.f);
  for (int i = lo; i < hi; ++i) {
    float di = dinv[i];
    float sn = di * di;
    const float4 tv = *(const float4*)&t[(size_t)i * HID_C + lane * 4];
    float4 acc = make_float4(tv.x * sn, tv.y * sn, tv.z * sn, tv.w * sn);
    int beg = offs[i], end = offs[i + 1];
    for (int p = beg; p < end; ++p) {
      int s = esrc[p];
      float wgt = enorm[p];
      const float4 v = *(const float4*)&t[(size_t)s * HID_C + lane * 4];
      acc.x += v.x * wgt; acc.y += v.y * wgt;
      acc.z += v.z * wgt; acc.w += v.w * wgt;
    }
    // h[i] = acc + bias; pooled sum accumulates h rows in ascending order
    gacc.x += acc.x + bv.x; gacc.y += acc.y + bv.y;
    gacc.z += acc.z + bv.z; gacc.w += acc.w + bv.w;
  }
  float inv = 1.0f / fmaxf((float)(hi - lo), 1.0f);
  gacc.x *= inv; gacc.y *= inv; gacc.z *= inv; gacc.w *= inv;
  *(float4*)&out[(size_t)g * HID_C + lane * 4] = gacc;
}

// ---------------- launch ----------------

extern "C" void kernel_launch(void* const* d_in, const int* in_sizes, int n_in,
                              void* d_out, int out_size, void* d_ws, size_t ws_size,
                              hipStream_t stream) {
  (void)in_sizes; (void)n_in; (void)out_size; (void)ws_size;
  const float* x  = (const float*)d_in[0];
  const float* W1 = (const float*)d_in[1];
  const float* b1 = (const float*)d_in[2];
  const float* W2 = (const float*)d_in[3];
  const float* b2 = (const float*)d_in[4];
  const int* edge_index = (const int*)d_in[5];
  const int* batch = (const int*)d_in[6];
  const int* e_src = edge_index;
  const int* e_dst = edge_index + N_EDGES_C;
  float* out = (float*)d_out;

  // workspace layout
  const size_t NCH = (size_t)N_NODES_C * HID_C;   // 51.2M elems
  unsigned short* t1 = (unsigned short*)d_ws;     // bf16 [N,256]  102.4 MB
  unsigned short* h1 = t1 + NCH;                  // bf16 [N,256]  102.4 MB
  float* t2     = (float*)(h1 + NCH);             // fp32 [N,256]  204.8 MB
  float* dinv   = t2 + NCH;
  int*   deg    = (int*)(dinv + N_NODES_C);
  int*   offs   = deg + N_NODES_C;
  int*   cursor = offs + (N_NODES_C + 64);
  int*   esrc   = cursor + N_NODES_C;
  float* enorm  = (float*)(esrc + N_EDGES_C);
  int*   bsums  = (int*)(enorm + N_EDGES_C);
  // W1T/W2T alias the cursor region (524 KB < 800 KB): cursor is dead after
  // scatter_kernel, and wprep_* launch AFTER scatter. 16B-aligned.
  unsigned short* W1T = (unsigned short*)cursor;
  unsigned short* W2T = W1T + (size_t)IN_CH_C * HID_C;

  const int NB = (N_NODES_C + 255) / 256;
  const int EB = (N_EDGES_C + 255) / 256;

  zero2_kernel<<<NB, 256, 0, stream>>>(deg, cursor, N_NODES_C);
  hist_kernel<<<EB, 256, 0, stream>>>(e_dst, deg, N_EDGES_C);
  scan1_kernel<<<NB, 256, 0, stream>>>(deg, offs, bsums, N_NODES_C);
  scan2_kernel<<<1, 1024, 0, stream>>>(bsums, NB);
  scan3_kernel<<<NB, 256, 0, stream>>>(offs, bsums, N_NODES_C);
  dinv_kernel<<<NB, 256, 0, stream>>>(deg, dinv, N_NODES_C);
  scatter_kernel<<<EB, 256, 0, stream>>>(e_src, e_dst, offs, cursor, dinv, esrc, enorm, N_EDGES_C);

  // weight prep (after scatter: W1T/W2T alias cursor)
  wprep_kernel<<<(IN_CH_C * HID_C + 255) / 256, 256, 0, stream>>>(W1, W1T, IN_CH_C, HID_C, IN_CH_C * HID_C);
  wprep_kernel<<<(HID_C * HID_C + 255) / 256, 256, 0, stream>>>(W2, W2T, HID_C, HID_C, HID_C * HID_C);

  dim3 g1((N_NODES_C + BM - 1) / BM);  // 1563 blocks, full-width N tiles
  gemm_kernel<0, 1><<<g1, 512, 0, stream>>>(x, W1T, t1, N_NODES_C, IN_CH_C);
  aggregate_bf_kernel<<<(N_NODES_C * 64 + 255) / 256, 256, 0, stream>>>(
      t1, h1, offs, esrc, enorm, dinv, b1);
  gemm_kernel<1, 0><<<g1, 512, 0, stream>>>(h1, W2T, t2, N_NODES_C, HID_C);
  agg_pool_kernel<<<(NUM_GRAPHS_C * 64 + 255) / 256, 256, 0, stream>>>(
      t2, offs, esrc, enorm, dinv, b2, batch, out);
}